// Round 3
// baseline (673.507 us; speedup 1.0000x reference)
//
#include <hip/hip_runtime.h>
#include <math.h>

// Problem constants (fixed by reference)
#define S   8000     // L = 20*20*20
#define BB  2
#define CC  96
#define DI  192      // d_inner
#define NS  16       // d_state
#define RK  6        // dt_rank
#define GG  6        // B * 3 directions
#define NC  25       // scan chunks
#define LC  320      // chunk length
#define ND  38       // dt_rank + 2*d_state
#define EBLK 8       // e's per scan block
#define NEB (DI/EBLK)// 24

// l -> pos mapping per direction.
__device__ __forceinline__ int pos_from_l(int dir, int l) {
  if (dir == 0) return l;
  int a  = l / 400;
  int r  = l - a * 400;
  int bq = r / 20;
  int cq = r - bq * 20;
  if (dir == 1) return cq * 400 + a * 20 + bq;   // (h=a, w=bq, d=cq)
  return bq * 400 + cq * 20 + a;                 // (w=a, d=bq, h=cq)
}

// 16-lane butterfly sum via DPP (all lanes end with the group sum)
__device__ __forceinline__ float red16(float x) {
  x += __int_as_float(__builtin_amdgcn_update_dpp(0, __float_as_int(x), 0xB1, 0xF, 0xF, true));  // quad_perm [1,0,3,2]
  x += __int_as_float(__builtin_amdgcn_update_dpp(0, __float_as_int(x), 0x4E, 0xF, 0xF, true));  // quad_perm [2,3,0,1]
  x += __int_as_float(__builtin_amdgcn_update_dpp(0, __float_as_int(x), 0x141, 0xF, 0xF, true)); // row_half_mirror
  x += __int_as_float(__builtin_amdgcn_update_dpp(0, __float_as_int(x), 0x140, 0xF, 0xF, true)); // row_mirror
  return x;
}

// ---------------- K0: double LayerNorm over channels (per position) -------
__global__ __launch_bounds__(256) void k_ln2(const float* __restrict__ x,
    const float* __restrict__ lnw, const float* __restrict__ lnb,
    const float* __restrict__ mlnw, const float* __restrict__ mlnb,
    float* __restrict__ xn) {
  int t = blockIdx.x * blockDim.x + threadIdx.x;
  if (t >= BB * S) return;
  int b = t / S, pos = t - b * S;
  const float* xp = x + (size_t)b * CC * S + pos;
  float s1 = 0.f, s2 = 0.f;
  for (int c = 0; c < CC; ++c) { float v = xp[(size_t)c * S]; s1 += v; s2 += v * v; }
  float u = s1 * (1.f / CC);
  float var = s2 * (1.f / CC) - u * u;
  float rstd = rsqrtf(var + 1e-6f);
  float t1 = 0.f, t2 = 0.f;
  for (int c = 0; c < CC; ++c) {
    float y1 = fmaf(lnw[c], (xp[(size_t)c * S] - u) * rstd, lnb[c]);
    t1 += y1; t2 += y1 * y1;
  }
  float u2 = t1 * (1.f / CC);
  float var2 = t2 * (1.f / CC) - u2 * u2;
  float rstd2 = rsqrtf(var2 + 1e-5f);
  float* o = xn + (size_t)t * CC;
  for (int c = 0; c < CC; ++c) {
    float y1 = fmaf(lnw[c], (xp[(size_t)c * S] - u) * rstd, lnb[c]);
    o[c] = fmaf(mlnw[c], (y1 - u2) * rstd2, mlnb[c]);
  }
}

// ---------------- single LayerNorm (B,C,S) -> (B*S,C) --------------------
__global__ __launch_bounds__(256) void k_ln1(const float* __restrict__ xi,
    const float* __restrict__ lnw, const float* __restrict__ lnb,
    float* __restrict__ out) {
  int t = blockIdx.x * blockDim.x + threadIdx.x;
  if (t >= BB * S) return;
  int b = t / S, pos = t - b * S;
  const float* xp = xi + (size_t)b * CC * S + pos;
  float s1 = 0.f, s2 = 0.f;
  for (int c = 0; c < CC; ++c) { float v = xp[(size_t)c * S]; s1 += v; s2 += v * v; }
  float u = s1 * (1.f / CC);
  float var = s2 * (1.f / CC) - u * u;
  float rstd = rsqrtf(var + 1e-6f);
  float* o = out + (size_t)t * CC;
  for (int c = 0; c < CC; ++c)
    o[c] = fmaf(lnw[c], (xp[(size_t)c * S] - u) * rstd, lnb[c]);
}

// ---------------- generic fp32 GEMM: C = act(A[M,K] @ Bw[N,K]^T + bias) ---
template <int ACT, bool BIAS, bool RESID, bool OUT_BCS>
__global__ __launch_bounds__(256) void k_gemm(const float* __restrict__ A,
    const float* __restrict__ Bw, const float* __restrict__ bias,
    const float* __restrict__ resid, float* __restrict__ Cmat,
    int M, int N, int K) {
  __shared__ float As[16][68];
  __shared__ float Bs[16][68];
  int tid = threadIdx.x;
  int tx = tid & 15, ty = tid >> 4;
  int m0 = blockIdx.x * 64, n0 = blockIdx.y * 64;
  float acc[4][4] = {};
  for (int kk = 0; kk < K; kk += 16) {
#pragma unroll
    for (int i = 0; i < 4; ++i) {
      int idx = tid + i * 256;
      int am = idx >> 4, ak = idx & 15;
      As[ak][am] = A[(size_t)(m0 + am) * K + kk + ak];
    }
#pragma unroll
    for (int i = 0; i < 4; ++i) {
      int idx = tid + i * 256;
      int bn = idx >> 4, bk = idx & 15;
      Bs[bk][bn] = (n0 + bn < N) ? Bw[(size_t)(n0 + bn) * K + kk + bk] : 0.f;
    }
    __syncthreads();
#pragma unroll
    for (int k = 0; k < 16; ++k) {
      float4 av = *(const float4*)&As[k][ty * 4];
      float4 bv = *(const float4*)&Bs[k][tx * 4];
      acc[0][0] = fmaf(av.x, bv.x, acc[0][0]);
      acc[0][1] = fmaf(av.x, bv.y, acc[0][1]);
      acc[0][2] = fmaf(av.x, bv.z, acc[0][2]);
      acc[0][3] = fmaf(av.x, bv.w, acc[0][3]);
      acc[1][0] = fmaf(av.y, bv.x, acc[1][0]);
      acc[1][1] = fmaf(av.y, bv.y, acc[1][1]);
      acc[1][2] = fmaf(av.y, bv.z, acc[1][2]);
      acc[1][3] = fmaf(av.y, bv.w, acc[1][3]);
      acc[2][0] = fmaf(av.z, bv.x, acc[2][0]);
      acc[2][1] = fmaf(av.z, bv.y, acc[2][1]);
      acc[2][2] = fmaf(av.z, bv.z, acc[2][2]);
      acc[2][3] = fmaf(av.z, bv.w, acc[2][3]);
      acc[3][0] = fmaf(av.w, bv.x, acc[3][0]);
      acc[3][1] = fmaf(av.w, bv.y, acc[3][1]);
      acc[3][2] = fmaf(av.w, bv.z, acc[3][2]);
      acc[3][3] = fmaf(av.w, bv.w, acc[3][3]);
    }
    __syncthreads();
  }
#pragma unroll
  for (int i = 0; i < 4; ++i) {
    int m = m0 + ty * 4 + i;
#pragma unroll
    for (int j = 0; j < 4; ++j) {
      int n = n0 + tx * 4 + j;
      if (n < N) {
        float v = acc[i][j];
        if (BIAS) v += bias[n];
        if (ACT == 1) v = 0.5f * v * (1.f + erff(v * 0.70710678118654752f));
        if (RESID || OUT_BCS) {
          int bb = m / S, pp = m - bb * S;
          size_t oidx = ((size_t)bb * CC + n) * S + pp;
          if (RESID) v += resid[oidx];
          if (OUT_BCS) { Cmat[oidx] = v; continue; }
        }
        Cmat[(size_t)m * N + n] = v;
      }
    }
  }
}

// ---------------- causal depthwise conv(4) + SiLU, gathered input --------
__global__ __launch_bounds__(256) void k_conv(const float* __restrict__ XZ,
    const float* __restrict__ cw, const float* __restrict__ cb,
    float* __restrict__ xc) {
  int t = blockIdx.x * blockDim.x + threadIdx.x;
  if (t >= GG * S * DI) return;
  int e = t % DI; int gl = t / DI; int l = gl % S; int g = gl / S;
  int b = g / 3, dir = g - (g / 3) * 3;
  float acc = cb[e];
#pragma unroll
  for (int k = 0; k < 4; ++k) {
    int ls = l + k - 3;
    if (ls >= 0) {
      int p = pos_from_l(dir, ls);
      acc = fmaf(cw[e * 4 + k], XZ[((size_t)b * S + p) * 384 + e], acc);
    }
  }
  float sg = 1.f / (1.f + __expf(-acc));
  xc[(size_t)gl * DI + e] = acc * sg;
}

// ---------------- k_prep: dt (softplus proj) + transposes ----------------
__global__ __launch_bounds__(256) void k_prep(const float* __restrict__ xc,
    const float* __restrict__ xdbl, const float* __restrict__ Wdt,
    const float* __restrict__ bdt, float* __restrict__ dtT,
    float* __restrict__ xcT, float* __restrict__ BCT) {
  __shared__ float xd[64][39];
  __shared__ float tile[64][65];
  int g = blockIdx.y;
  int l0 = blockIdx.x * 64;
  int tid = threadIdx.x;
  for (int idx = tid; idx < 64 * ND; idx += 256) {
    int i = idx / ND, c2 = idx - i * ND;
    xd[i][c2] = xdbl[((size_t)g * S + l0 + i) * ND + c2];
  }
  __syncthreads();
  int l = tid & 63;
  int jo = tid >> 6;
#pragma unroll
  for (int j0 = 0; j0 < 32; j0 += 4) {
    int j = j0 + jo;
    BCT[((size_t)g * 32 + j) * S + l0 + l] = xd[l][RK + j];
  }
  for (int e0 = 0; e0 < DI; e0 += 4) {
    int e = e0 + jo;
    float a = bdt[e];
#pragma unroll
    for (int r = 0; r < RK; ++r) a = fmaf(Wdt[e * RK + r], xd[l][r], a);
    float sp = (a > 20.f) ? a : log1pf(__expf(a));
    dtT[((size_t)g * DI + e) * S + l0 + l] = sp;
  }
  for (int e0 = 0; e0 < DI; e0 += 64) {
    __syncthreads();
#pragma unroll
    for (int p = 0; p < 16; ++p) {
      int i = jo * 16 + p;
      int ec = tid & 63;
      tile[i][ec] = xc[((size_t)g * S + l0 + i) * DI + e0 + ec];
    }
    __syncthreads();
#pragma unroll
    for (int p = 0; p < 16; ++p) {
      int er = jo * 16 + p;
      int lc = tid & 63;
      xcT[((size_t)g * DI + e0 + er) * S + l0 + lc] = tile[lc][er];
    }
  }
}

// ---------------- K5A: per-chunk (prodA, end-state), LDS-staged ----------
__global__ __launch_bounds__(128) void k_scanA(const float* __restrict__ dtT,
    const float* __restrict__ xcT, const float* __restrict__ BCT,
    const float* __restrict__ A_log, float* __restrict__ PA, float* __restrict__ EA) {
  __shared__ float sdt[EBLK][LC];
  __shared__ float sxc[EBLK][LC];
  __shared__ float sB[NS][324];   // stride 324: b128-aligned, 2-way bank alias (free)
  int bid = blockIdx.x;
  int eb = bid % NEB; int rest = bid / NEB; int c = rest % NC; int g = rest / NC;
  int tid = threadIdx.x;
  // stage dt/xc: EBLK rows x 80 float4, coalesced
  for (int i = tid; i < EBLK * (LC / 4); i += 128) {
    int row = i / (LC / 4), col = i - row * (LC / 4);
    size_t gbase = ((size_t)(g * DI + eb * EBLK + row)) * S + c * LC + col * 4;
    *(float4*)&sdt[row][col * 4] = *(const float4*)(dtT + gbase);
    *(float4*)&sxc[row][col * 4] = *(const float4*)(xcT + gbase);
  }
  // stage B: 16 rows x 80 float4
  for (int i = tid; i < NS * (LC / 4); i += 128) {
    int row = i / (LC / 4), col = i - row * (LC / 4);
    *(float4*)&sB[row][col * 4] =
        *(const float4*)(BCT + ((size_t)(g * 32 + row)) * S + c * LC + col * 4);
  }
  __syncthreads();
  int s = tid & 15, el = tid >> 4;           // el 0..7
  int e = eb * EBLK + el;
  float A_es = -__expf(A_log[e * NS + s]);
  float E = 0.f, T = 0.f;
#pragma unroll 4
  for (int l = 0; l < LC; ++l) {
    float d = sdt[el][l], xv = sxc[el][l], b = sB[s][l];
    float q = __expf(d * A_es);
    E = fmaf(q, E, d * xv * b);
    T += d;
  }
  int sidx = ((g * NC + c) * DI + e) * NS + s;
  PA[sidx] = __expf(A_es * T);
  EA[sidx] = E;
}

// ---------------- K5B: inter-chunk sequential combine --------------------
__global__ __launch_bounds__(256) void k_scanB(const float* __restrict__ PA,
    const float* __restrict__ EA, float* __restrict__ Hin) {
  int idx = blockIdx.x * blockDim.x + threadIdx.x;
  if (idx >= GG * DI * NS) return;
  int g = idx / (DI * NS); int es = idx - g * (DI * NS);
  float h = 0.f;
  for (int c = 0; c < NC; ++c) {
    int sidx = (g * NC + c) * DI * NS + es;
    Hin[sidx] = h;
    h = fmaf(PA[sidx], h, EA[sidx]);
  }
}

// ---------------- K5C: rescan + y = sum_s h*Cm + Dp skip, LDS-staged -----
__global__ __launch_bounds__(128) void k_scanC(const float* __restrict__ dtT,
    const float* __restrict__ xcT, const float* __restrict__ BCT,
    const float* __restrict__ Hin, const float* __restrict__ A_log,
    const float* __restrict__ Dp, float* __restrict__ yg) {
  __shared__ float sdt[EBLK][LC];
  __shared__ float sxc[EBLK][LC];
  __shared__ float sB[NS][324];
  __shared__ float sC[NS][324];
  int bid = blockIdx.x;
  int eb = bid % NEB; int rest = bid / NEB; int c = rest % NC; int g = rest / NC;
  int tid = threadIdx.x;
  for (int i = tid; i < EBLK * (LC / 4); i += 128) {
    int row = i / (LC / 4), col = i - row * (LC / 4);
    size_t gbase = ((size_t)(g * DI + eb * EBLK + row)) * S + c * LC + col * 4;
    *(float4*)&sdt[row][col * 4] = *(const float4*)(dtT + gbase);
    *(float4*)&sxc[row][col * 4] = *(const float4*)(xcT + gbase);
  }
  for (int i = tid; i < NS * (LC / 4); i += 128) {
    int row = i / (LC / 4), col = i - row * (LC / 4);
    size_t gb = ((size_t)(g * 32 + row)) * S + c * LC + col * 4;
    *(float4*)&sB[row][col * 4] = *(const float4*)(BCT + gb);
    *(float4*)&sC[row][col * 4] = *(const float4*)(BCT + gb + (size_t)16 * S);
  }
  __syncthreads();
  int s = tid & 15, el = tid >> 4;
  int e = eb * EBLK + el;
  float A_es = -__expf(A_log[e * NS + s]);
  int sidx = ((g * NC + c) * DI + e) * NS + s;
  float h = Hin[sidx];
  float dpe = Dp[e];
  float* yo = yg + ((size_t)(g / 3) * S + c * LC) * 576 + (g - (g / 3) * 3) * DI + e;
#pragma unroll 4
  for (int l = 0; l < LC; ++l) {
    float d = sdt[el][l], xv = sxc[el][l], b = sB[s][l], cm = sC[s][l];
    float q = __expf(d * A_es);
    h = fmaf(q, h, d * xv * b);
    float p = red16(h * cm);
    if (s == 0) yo[(size_t)l * 576] = fmaf(xv, dpe, p);
  }
}

// ---------------- gate pass: yg *= silu(z gathered) ----------------------
__global__ __launch_bounds__(256) void k_gate(float* __restrict__ yg,
    const float* __restrict__ XZ) {
  int t = blockIdx.x * blockDim.x + threadIdx.x;
  if (t >= BB * S * 144) return;
  int row = t / 144;
  int j4 = t - row * 144;
  int j0 = j4 * 4;
  int dir = j0 / 192; int e0 = j0 - dir * 192;
  int b = row / S; int l = row - b * S;
  int p = pos_from_l(dir, l);
  const float4 z4 = *(const float4*)&XZ[((size_t)b * S + p) * 384 + DI + e0];
  float4* yp = (float4*)(yg + (size_t)row * 576 + j0);
  float4 y4 = *yp;
  y4.x *= z4.x / (1.f + __expf(-z4.x));
  y4.y *= z4.y / (1.f + __expf(-z4.y));
  y4.z *= z4.z / (1.f + __expf(-z4.z));
  y4.w *= z4.w / (1.f + __expf(-z4.w));
  *yp = y4;
}

// ---------------- fold Wout into proj_w: Mcat[o, dir*192+e] --------------
__global__ __launch_bounds__(256) void k_foldW(const float* __restrict__ proj_w,
    const float* __restrict__ Wout, float* __restrict__ Mcat) {
  int t = blockIdx.x * blockDim.x + threadIdx.x;
  if (t >= CC * 576) return;
  int o = t / 576; int j = t - o * 576; int dir = j / DI; int e = j - dir * DI;
  float a = 0.f;
  for (int c2 = 0; c2 < CC; ++c2)
    a = fmaf(proj_w[o * 288 + dir * CC + c2], Wout[c2 * DI + e], a);
  Mcat[t] = a;
}

extern "C" void kernel_launch(void* const* d_in, const int* in_sizes, int n_in,
                              void* d_out, int out_size, void* d_ws, size_t ws_size,
                              hipStream_t stream) {
  const float* x      = (const float*)d_in[0];
  const float* ln_w   = (const float*)d_in[1];
  const float* ln_b   = (const float*)d_in[2];
  const float* mln_w  = (const float*)d_in[3];
  const float* mln_b  = (const float*)d_in[4];
  const float* Win    = (const float*)d_in[5];
  const float* conv_w = (const float*)d_in[6];
  const float* conv_b = (const float*)d_in[7];
  const float* Wx     = (const float*)d_in[8];
  const float* Wdt    = (const float*)d_in[9];
  const float* bdt    = (const float*)d_in[10];
  const float* A_log  = (const float*)d_in[11];
  const float* Dp     = (const float*)d_in[12];
  const float* Wout   = (const float*)d_in[13];
  const float* proj_w = (const float*)d_in[14];
  const float* proj_b = (const float*)d_in[15];
  const float* fc1_w  = (const float*)d_in[16];
  const float* fc1_b  = (const float*)d_in[17];
  const float* fc2_w  = (const float*)d_in[18];
  const float* fc2_b  = (const float*)d_in[19];

  float* ws = (float*)d_ws;
  size_t off = 0;
  float* xn   = ws + off; off += (size_t)BB * S * CC;
  float* XZ   = ws + off; off += (size_t)BB * S * 384;
  float* xc   = ws + off; off += (size_t)GG * S * DI;
  float* xdbl = ws + off; off += (size_t)GG * S * ND;
  float* dtT  = ws + off; off += (size_t)GG * S * DI;
  float* xcT  = ws + off; off += (size_t)GG * S * DI;
  float* PA   = ws + off; off += (size_t)GG * NC * DI * NS;
  float* EA   = ws + off; off += (size_t)GG * NC * DI * NS;
  float* Hin  = ws + off; off += (size_t)GG * NC * DI * NS;
  float* Mcat = ws + off; off += (size_t)CC * 576;
  if (ws_size < off * sizeof(float)) return;
  float* BCT  = xn;     // xn dead after Win GEMM; BCT = GG*32*S floats exactly
  float* xln2 = xn;     // BCT dead after scanC
  float* yg   = xc;     // xc dead after prep; yg written by scanC
  float* h1   = XZ;     // z dead after gate
  float* ores = dtT;    // dtT dead after scanC

  k_ln2<<<(BB * S + 255) / 256, 256, 0, stream>>>(x, ln_w, ln_b, mln_w, mln_b, xn);
  k_gemm<0, false, false, false><<<dim3(BB * S / 64, 384 / 64), 256, 0, stream>>>(
      xn, Win, nullptr, nullptr, XZ, BB * S, 384, CC);
  k_conv<<<(GG * S * DI + 255) / 256, 256, 0, stream>>>(XZ, conv_w, conv_b, xc);
  k_gemm<0, false, false, false><<<dim3(GG * S / 64, 1), 256, 0, stream>>>(
      xc, Wx, nullptr, nullptr, xdbl, GG * S, ND, DI);
  k_prep<<<dim3(S / 64, GG), 256, 0, stream>>>(xc, xdbl, Wdt, bdt, dtT, xcT, BCT);
  k_scanA<<<GG * NC * NEB, 128, 0, stream>>>(dtT, xcT, BCT, A_log, PA, EA);
  k_scanB<<<(GG * DI * NS + 255) / 256, 256, 0, stream>>>(PA, EA, Hin);
  k_scanC<<<GG * NC * NEB, 128, 0, stream>>>(dtT, xcT, BCT, Hin, A_log, Dp, yg);
  k_gate<<<(BB * S * 144 + 255) / 256, 256, 0, stream>>>(yg, XZ);
  k_foldW<<<(CC * 576 + 255) / 256, 256, 0, stream>>>(proj_w, Wout, Mcat);
  k_gemm<0, true, true, true><<<dim3(BB * S / 64, 2), 256, 0, stream>>>(
      yg, Mcat, proj_b, x, ores, BB * S, CC, 576);
  k_ln1<<<(BB * S + 255) / 256, 256, 0, stream>>>(ores, ln_w, ln_b, xln2);
  k_gemm<1, true, false, false><<<dim3(BB * S / 64, 384 / 64), 256, 0, stream>>>(
      xln2, fc1_w, fc1_b, nullptr, h1, BB * S, 384, CC);
  k_gemm<0, true, true, true><<<dim3(BB * S / 64, 2), 256, 0, stream>>>(
      h1, fc2_w, fc2_b, ores, (float*)d_out, BB * S, CC, 384);
}

// Round 4
// 502.834 us; speedup vs baseline: 1.3394x; 1.3394x over previous
//
#include <hip/hip_runtime.h>
#include <math.h>

// Problem constants (fixed by reference)
#define S   8000     // L = 20*20*20
#define BB  2
#define CC  96
#define DI  192      // d_inner
#define NS  16       // d_state
#define RK  6        // dt_rank
#define GG  6        // B * 3 directions
#define NC  100      // scan chunks
#define LC  80       // chunk length
#define ND  38       // dt_rank + 2*d_state

// l -> pos mapping per direction.
__device__ __forceinline__ int pos_from_l(int dir, int l) {
  if (dir == 0) return l;
  int a  = l / 400;
  int r  = l - a * 400;
  int bq = r / 20;
  int cq = r - bq * 20;
  if (dir == 1) return cq * 400 + a * 20 + bq;   // (h=a, w=bq, d=cq)
  return bq * 400 + cq * 20 + a;                 // (w=a, d=bq, h=cq)
}

// ---------------- K0: double LayerNorm over channels (per position) -------
__global__ __launch_bounds__(256) void k_ln2(const float* __restrict__ x,
    const float* __restrict__ lnw, const float* __restrict__ lnb,
    const float* __restrict__ mlnw, const float* __restrict__ mlnb,
    float* __restrict__ xn) {
  int t = blockIdx.x * blockDim.x + threadIdx.x;
  if (t >= BB * S) return;
  int b = t / S, pos = t - b * S;
  const float* xp = x + (size_t)b * CC * S + pos;
  float s1 = 0.f, s2 = 0.f;
  for (int c = 0; c < CC; ++c) { float v = xp[(size_t)c * S]; s1 += v; s2 += v * v; }
  float u = s1 * (1.f / CC);
  float var = s2 * (1.f / CC) - u * u;
  float rstd = rsqrtf(var + 1e-6f);
  float t1 = 0.f, t2 = 0.f;
  for (int c = 0; c < CC; ++c) {
    float y1 = fmaf(lnw[c], (xp[(size_t)c * S] - u) * rstd, lnb[c]);
    t1 += y1; t2 += y1 * y1;
  }
  float u2 = t1 * (1.f / CC);
  float var2 = t2 * (1.f / CC) - u2 * u2;
  float rstd2 = rsqrtf(var2 + 1e-5f);
  float* o = xn + (size_t)t * CC;
  for (int c = 0; c < CC; ++c) {
    float y1 = fmaf(lnw[c], (xp[(size_t)c * S] - u) * rstd, lnb[c]);
    o[c] = fmaf(mlnw[c], (y1 - u2) * rstd2, mlnb[c]);
  }
}

// ---------------- single LayerNorm (B,C,S) -> (B*S,C) --------------------
__global__ __launch_bounds__(256) void k_ln1(const float* __restrict__ xi,
    const float* __restrict__ lnw, const float* __restrict__ lnb,
    float* __restrict__ out) {
  int t = blockIdx.x * blockDim.x + threadIdx.x;
  if (t >= BB * S) return;
  int b = t / S, pos = t - b * S;
  const float* xp = xi + (size_t)b * CC * S + pos;
  float s1 = 0.f, s2 = 0.f;
  for (int c = 0; c < CC; ++c) { float v = xp[(size_t)c * S]; s1 += v; s2 += v * v; }
  float u = s1 * (1.f / CC);
  float var = s2 * (1.f / CC) - u * u;
  float rstd = rsqrtf(var + 1e-6f);
  float* o = out + (size_t)t * CC;
  for (int c = 0; c < CC; ++c)
    o[c] = fmaf(lnw[c], (xp[(size_t)c * S] - u) * rstd, lnb[c]);
}

// ---------------- generic fp32 GEMM: C = act(A[M,K] @ Bw[N,K]^T + bias) ---
template <int ACT, bool BIAS, bool RESID, bool OUT_BCS>
__global__ __launch_bounds__(256) void k_gemm(const float* __restrict__ A,
    const float* __restrict__ Bw, const float* __restrict__ bias,
    const float* __restrict__ resid, float* __restrict__ Cmat,
    int M, int N, int K) {
  __shared__ float As[16][68];
  __shared__ float Bs[16][68];
  int tid = threadIdx.x;
  int tx = tid & 15, ty = tid >> 4;
  int m0 = blockIdx.x * 64, n0 = blockIdx.y * 64;
  float acc[4][4] = {};
  for (int kk = 0; kk < K; kk += 16) {
#pragma unroll
    for (int i = 0; i < 4; ++i) {
      int idx = tid + i * 256;
      int am = idx >> 4, ak = idx & 15;
      As[ak][am] = A[(size_t)(m0 + am) * K + kk + ak];
    }
#pragma unroll
    for (int i = 0; i < 4; ++i) {
      int idx = tid + i * 256;
      int bn = idx >> 4, bk = idx & 15;
      Bs[bk][bn] = (n0 + bn < N) ? Bw[(size_t)(n0 + bn) * K + kk + bk] : 0.f;
    }
    __syncthreads();
#pragma unroll
    for (int k = 0; k < 16; ++k) {
      float4 av = *(const float4*)&As[k][ty * 4];
      float4 bv = *(const float4*)&Bs[k][tx * 4];
      acc[0][0] = fmaf(av.x, bv.x, acc[0][0]);
      acc[0][1] = fmaf(av.x, bv.y, acc[0][1]);
      acc[0][2] = fmaf(av.x, bv.z, acc[0][2]);
      acc[0][3] = fmaf(av.x, bv.w, acc[0][3]);
      acc[1][0] = fmaf(av.y, bv.x, acc[1][0]);
      acc[1][1] = fmaf(av.y, bv.y, acc[1][1]);
      acc[1][2] = fmaf(av.y, bv.z, acc[1][2]);
      acc[1][3] = fmaf(av.y, bv.w, acc[1][3]);
      acc[2][0] = fmaf(av.z, bv.x, acc[2][0]);
      acc[2][1] = fmaf(av.z, bv.y, acc[2][1]);
      acc[2][2] = fmaf(av.z, bv.z, acc[2][2]);
      acc[2][3] = fmaf(av.z, bv.w, acc[2][3]);
      acc[3][0] = fmaf(av.w, bv.x, acc[3][0]);
      acc[3][1] = fmaf(av.w, bv.y, acc[3][1]);
      acc[3][2] = fmaf(av.w, bv.z, acc[3][2]);
      acc[3][3] = fmaf(av.w, bv.w, acc[3][3]);
    }
    __syncthreads();
  }
#pragma unroll
  for (int i = 0; i < 4; ++i) {
    int m = m0 + ty * 4 + i;
#pragma unroll
    for (int j = 0; j < 4; ++j) {
      int n = n0 + tx * 4 + j;
      if (n < N) {
        float v = acc[i][j];
        if (BIAS) v += bias[n];
        if (ACT == 1) v = 0.5f * v * (1.f + erff(v * 0.70710678118654752f));
        if (RESID || OUT_BCS) {
          int bb = m / S, pp = m - bb * S;
          size_t oidx = ((size_t)bb * CC + n) * S + pp;
          if (RESID) v += resid[oidx];
          if (OUT_BCS) { Cmat[oidx] = v; continue; }
        }
        Cmat[(size_t)m * N + n] = v;
      }
    }
  }
}

// ---------------- causal depthwise conv(4) + SiLU, gathered input --------
__global__ __launch_bounds__(256) void k_conv(const float* __restrict__ XZ,
    const float* __restrict__ cw, const float* __restrict__ cb,
    float* __restrict__ xc) {
  int t = blockIdx.x * blockDim.x + threadIdx.x;
  if (t >= GG * S * DI) return;
  int e = t % DI; int gl = t / DI; int l = gl % S; int g = gl / S;
  int b = g / 3, dir = g - (g / 3) * 3;
  float acc = cb[e];
#pragma unroll
  for (int k = 0; k < 4; ++k) {
    int ls = l + k - 3;
    if (ls >= 0) {
      int p = pos_from_l(dir, ls);
      acc = fmaf(cw[e * 4 + k], XZ[((size_t)b * S + p) * 384 + e], acc);
    }
  }
  float sg = 1.f / (1.f + __expf(-acc));
  xc[(size_t)gl * DI + e] = acc * sg;
}

// ======== scan kernels: 1 thread = (g, e, chunk), 16 states in regs ======
// LDS tile: sBC[l][j]: j 0..5 = dt_r, j 8..23 = B, j 24..39 = C (b128-aligned)
__device__ __forceinline__ void stage_bc(float (*sBC)[40],
    const float* __restrict__ xdbl, int g, int c, int tid) {
  const float* src = xdbl + ((size_t)g * S + c * LC) * ND;
  for (int i = tid; i < LC * ND; i += 192) {
    int row = i / ND, col = i - row * ND;
    int dst = (col < RK) ? col : col + 2;
    sBC[row][dst] = src[(size_t)row * ND + col];
  }
}

__global__ __launch_bounds__(192) void k_scanA(const float* __restrict__ xc,
    const float* __restrict__ xdbl, const float* __restrict__ Wdt,
    const float* __restrict__ bdt, const float* __restrict__ A_log,
    float* __restrict__ PA, float* __restrict__ EA) {
  __shared__ float sBC[LC][40];
  int c = blockIdx.x, g = blockIdx.y;
  int e = threadIdx.x;
  stage_bc(sBC, xdbl, g, c, e);
  float wdt[RK];
#pragma unroll
  for (int r = 0; r < RK; ++r) wdt[r] = Wdt[e * RK + r];
  float bde = bdt[e];
  float Aes[NS];
#pragma unroll
  for (int s = 0; s < NS; ++s) Aes[s] = -__expf(A_log[e * NS + s]);
  float h[NS];
#pragma unroll
  for (int s = 0; s < NS; ++s) h[s] = 0.f;
  float T = 0.f;
  const float* xptr = xc + ((size_t)g * S + c * LC) * DI + e;
  __syncthreads();
  for (int l0 = 0; l0 < LC; l0 += 8) {
    float xb[8];
#pragma unroll
    for (int j = 0; j < 8; ++j) xb[j] = xptr[(size_t)(l0 + j) * DI];
#pragma unroll
    for (int j = 0; j < 8; ++j) {
      int l = l0 + j;
      float a = bde;
      float4 r0 = *(const float4*)&sBC[l][0];
      float2 r1 = *(const float2*)&sBC[l][4];
      a = fmaf(wdt[0], r0.x, a); a = fmaf(wdt[1], r0.y, a);
      a = fmaf(wdt[2], r0.z, a); a = fmaf(wdt[3], r0.w, a);
      a = fmaf(wdt[4], r1.x, a); a = fmaf(wdt[5], r1.y, a);
      float d = (a > 20.f) ? a : log1pf(__expf(a));
      float w = d * xb[j];
      T += d;
      float4 B0 = *(const float4*)&sBC[l][8];
      float4 B1 = *(const float4*)&sBC[l][12];
      float4 B2 = *(const float4*)&sBC[l][16];
      float4 B3 = *(const float4*)&sBC[l][20];
      float bs[16] = {B0.x, B0.y, B0.z, B0.w, B1.x, B1.y, B1.z, B1.w,
                      B2.x, B2.y, B2.z, B2.w, B3.x, B3.y, B3.z, B3.w};
#pragma unroll
      for (int s = 0; s < NS; ++s) {
        float q = __expf(d * Aes[s]);
        h[s] = fmaf(q, h[s], w * bs[s]);
      }
    }
  }
  float* pp = PA + (((size_t)g * NC + c) * DI + e) * NS;
  float* ep = EA + (((size_t)g * NC + c) * DI + e) * NS;
#pragma unroll
  for (int s = 0; s < NS; ++s) { pp[s] = __expf(Aes[s] * T); ep[s] = h[s]; }
}

// inter-chunk sequential combine (Hin may alias PA: read-before-write order)
__global__ __launch_bounds__(256) void k_scanB(const float* __restrict__ PA,
    const float* __restrict__ EA, float* __restrict__ Hin) {
  int idx = blockIdx.x * blockDim.x + threadIdx.x;
  if (idx >= GG * DI * NS) return;
  int g = idx / (DI * NS); int es = idx - g * (DI * NS);
  float h = 0.f;
  for (int c = 0; c < NC; ++c) {
    size_t sidx = ((size_t)g * NC + c) * DI * NS + es;
    float p = PA[sidx];
    float ea = EA[sidx];
    Hin[sidx] = h;
    h = fmaf(p, h, ea);
  }
}

__global__ __launch_bounds__(192) void k_scanC(const float* __restrict__ xc,
    const float* __restrict__ xdbl, const float* __restrict__ Wdt,
    const float* __restrict__ bdt, const float* __restrict__ A_log,
    const float* __restrict__ Hin, const float* __restrict__ Dp,
    float* __restrict__ yg) {
  __shared__ float sBC[LC][40];
  int c = blockIdx.x, g = blockIdx.y;
  int e = threadIdx.x;
  stage_bc(sBC, xdbl, g, c, e);
  float wdt[RK];
#pragma unroll
  for (int r = 0; r < RK; ++r) wdt[r] = Wdt[e * RK + r];
  float bde = bdt[e];
  float dpe = Dp[e];
  float Aes[NS];
#pragma unroll
  for (int s = 0; s < NS; ++s) Aes[s] = -__expf(A_log[e * NS + s]);
  float h[NS];
  const float* hp = Hin + (((size_t)g * NC + c) * DI + e) * NS;
#pragma unroll
  for (int s = 0; s < NS; ++s) h[s] = hp[s];
  const float* xptr = xc + ((size_t)g * S + c * LC) * DI + e;
  int b = g / 3, dir = g - (g / 3) * 3;
  float* yo = yg + ((size_t)b * S + c * LC) * 576 + dir * DI + e;
  __syncthreads();
  for (int l0 = 0; l0 < LC; l0 += 8) {
    float xb[8];
#pragma unroll
    for (int j = 0; j < 8; ++j) xb[j] = xptr[(size_t)(l0 + j) * DI];
#pragma unroll
    for (int j = 0; j < 8; ++j) {
      int l = l0 + j;
      float a = bde;
      float4 r0 = *(const float4*)&sBC[l][0];
      float2 r1 = *(const float2*)&sBC[l][4];
      a = fmaf(wdt[0], r0.x, a); a = fmaf(wdt[1], r0.y, a);
      a = fmaf(wdt[2], r0.z, a); a = fmaf(wdt[3], r0.w, a);
      a = fmaf(wdt[4], r1.x, a); a = fmaf(wdt[5], r1.y, a);
      float d = (a > 20.f) ? a : log1pf(__expf(a));
      float xv = xb[j];
      float w = d * xv;
      float4 B0 = *(const float4*)&sBC[l][8];
      float4 B1 = *(const float4*)&sBC[l][12];
      float4 B2 = *(const float4*)&sBC[l][16];
      float4 B3 = *(const float4*)&sBC[l][20];
      float4 C0 = *(const float4*)&sBC[l][24];
      float4 C1 = *(const float4*)&sBC[l][28];
      float4 C2 = *(const float4*)&sBC[l][32];
      float4 C3 = *(const float4*)&sBC[l][36];
      float bs[16] = {B0.x, B0.y, B0.z, B0.w, B1.x, B1.y, B1.z, B1.w,
                      B2.x, B2.y, B2.z, B2.w, B3.x, B3.y, B3.z, B3.w};
      float cs[16] = {C0.x, C0.y, C0.z, C0.w, C1.x, C1.y, C1.z, C1.w,
                      C2.x, C2.y, C2.z, C2.w, C3.x, C3.y, C3.z, C3.w};
      float y0 = xv * dpe, y1 = 0.f, y2 = 0.f, y3 = 0.f;
#pragma unroll
      for (int s = 0; s < NS; s += 4) {
        float q0 = __expf(d * Aes[s + 0]);
        float q1 = __expf(d * Aes[s + 1]);
        float q2 = __expf(d * Aes[s + 2]);
        float q3 = __expf(d * Aes[s + 3]);
        h[s + 0] = fmaf(q0, h[s + 0], w * bs[s + 0]);
        h[s + 1] = fmaf(q1, h[s + 1], w * bs[s + 1]);
        h[s + 2] = fmaf(q2, h[s + 2], w * bs[s + 2]);
        h[s + 3] = fmaf(q3, h[s + 3], w * bs[s + 3]);
        y0 = fmaf(h[s + 0], cs[s + 0], y0);
        y1 = fmaf(h[s + 1], cs[s + 1], y1);
        y2 = fmaf(h[s + 2], cs[s + 2], y2);
        y3 = fmaf(h[s + 3], cs[s + 3], y3);
      }
      yo[(size_t)l * 576] = (y0 + y1) + (y2 + y3);
    }
  }
}

// ---------------- gate pass: yg *= silu(z gathered) ----------------------
__global__ __launch_bounds__(256) void k_gate(float* __restrict__ yg,
    const float* __restrict__ XZ) {
  int t = blockIdx.x * blockDim.x + threadIdx.x;
  if (t >= BB * S * 144) return;
  int row = t / 144;
  int j4 = t - row * 144;
  int j0 = j4 * 4;
  int dir = j0 / 192; int e0 = j0 - dir * 192;
  int b = row / S; int l = row - b * S;
  int p = pos_from_l(dir, l);
  const float4 z4 = *(const float4*)&XZ[((size_t)b * S + p) * 384 + DI + e0];
  float4* yp = (float4*)(yg + (size_t)row * 576 + j0);
  float4 y4 = *yp;
  y4.x *= z4.x / (1.f + __expf(-z4.x));
  y4.y *= z4.y / (1.f + __expf(-z4.y));
  y4.z *= z4.z / (1.f + __expf(-z4.z));
  y4.w *= z4.w / (1.f + __expf(-z4.w));
  *yp = y4;
}

// ---------------- fold Wout into proj_w: Mcat[o, dir*192+e] --------------
__global__ __launch_bounds__(256) void k_foldW(const float* __restrict__ proj_w,
    const float* __restrict__ Wout, float* __restrict__ Mcat) {
  int t = blockIdx.x * blockDim.x + threadIdx.x;
  if (t >= CC * 576) return;
  int o = t / 576; int j = t - o * 576; int dir = j / DI; int e = j - dir * DI;
  float a = 0.f;
  for (int c2 = 0; c2 < CC; ++c2)
    a = fmaf(proj_w[o * 288 + dir * CC + c2], Wout[c2 * DI + e], a);
  Mcat[t] = a;
}

extern "C" void kernel_launch(void* const* d_in, const int* in_sizes, int n_in,
                              void* d_out, int out_size, void* d_ws, size_t ws_size,
                              hipStream_t stream) {
  const float* x      = (const float*)d_in[0];
  const float* ln_w   = (const float*)d_in[1];
  const float* ln_b   = (const float*)d_in[2];
  const float* mln_w  = (const float*)d_in[3];
  const float* mln_b  = (const float*)d_in[4];
  const float* Win    = (const float*)d_in[5];
  const float* conv_w = (const float*)d_in[6];
  const float* conv_b = (const float*)d_in[7];
  const float* Wx     = (const float*)d_in[8];
  const float* Wdt    = (const float*)d_in[9];
  const float* bdt    = (const float*)d_in[10];
  const float* A_log  = (const float*)d_in[11];
  const float* Dp     = (const float*)d_in[12];
  const float* Wout   = (const float*)d_in[13];
  const float* proj_w = (const float*)d_in[14];
  const float* proj_b = (const float*)d_in[15];
  const float* fc1_w  = (const float*)d_in[16];
  const float* fc1_b  = (const float*)d_in[17];
  const float* fc2_w  = (const float*)d_in[18];
  const float* fc2_b  = (const float*)d_in[19];

  float* ws = (float*)d_ws;
  size_t off = 0;
  float* xn   = ws + off; off += (size_t)BB * S * CC;      // 1.536M
  float* XZ   = ws + off; off += (size_t)BB * S * 384;     // 6.144M
  float* xc   = ws + off; off += (size_t)GG * S * DI;      // 9.216M
  float* xdbl = ws + off; off += (size_t)GG * S * ND;      // 1.824M
  float* PA   = ws + off; off += (size_t)GG * NC * DI * NS; // 1.8432M
  float* EA   = ws + off; off += (size_t)GG * NC * DI * NS; // 1.8432M
  float* yg   = ws + off; off += (size_t)BB * S * 576;     // 9.216M
  float* Mcat = ws + off; off += (size_t)CC * 576;
  if (ws_size < off * sizeof(float)) return;               // ~127 MB; guard
  float* Hin  = PA;     // in-place in scanB (read-before-write per element)
  float* ores = xn;     // xn dead after Win GEMM
  float* xln2 = xc;     // xc dead after scanC
  float* h1   = XZ;     // XZ dead after gate

  k_ln2<<<(BB * S + 255) / 256, 256, 0, stream>>>(x, ln_w, ln_b, mln_w, mln_b, xn);
  k_gemm<0, false, false, false><<<dim3(BB * S / 64, 384 / 64), 256, 0, stream>>>(
      xn, Win, nullptr, nullptr, XZ, BB * S, 384, CC);
  k_conv<<<(GG * S * DI + 255) / 256, 256, 0, stream>>>(XZ, conv_w, conv_b, xc);
  k_gemm<0, false, false, false><<<dim3(GG * S / 64, 1), 256, 0, stream>>>(
      xc, Wx, nullptr, nullptr, xdbl, GG * S, ND, DI);
  k_scanA<<<dim3(NC, GG), 192, 0, stream>>>(xc, xdbl, Wdt, bdt, A_log, PA, EA);
  k_scanB<<<(GG * DI * NS + 255) / 256, 256, 0, stream>>>(PA, EA, Hin);
  k_scanC<<<dim3(NC, GG), 192, 0, stream>>>(xc, xdbl, Wdt, bdt, A_log, Hin, Dp, yg);
  k_gate<<<(BB * S * 144 + 255) / 256, 256, 0, stream>>>(yg, XZ);
  k_foldW<<<(CC * 576 + 255) / 256, 256, 0, stream>>>(proj_w, Wout, Mcat);
  k_gemm<0, true, true, true><<<dim3(BB * S / 64, 2), 256, 0, stream>>>(
      yg, Mcat, proj_b, x, ores, BB * S, CC, 576);
  k_ln1<<<(BB * S + 255) / 256, 256, 0, stream>>>(ores, ln_w, ln_b, xln2);
  k_gemm<1, true, false, false><<<dim3(BB * S / 64, 384 / 64), 256, 0, stream>>>(
      xln2, fc1_w, fc1_b, nullptr, h1, BB * S, 384, CC);
  k_gemm<0, true, true, true><<<dim3(BB * S / 64, 2), 256, 0, stream>>>(
      h1, fc2_w, fc2_b, ores, (float*)d_out, BB * S, CC, 384);
}

// Round 5
// 425.984 us; speedup vs baseline: 1.5811x; 1.1804x over previous
//
#include <hip/hip_runtime.h>
#include <math.h>

// Problem constants (fixed by reference)
#define S   8000     // L = 20*20*20
#define BB  2
#define CC  96
#define DI  192      // d_inner
#define NS  16       // d_state
#define RK  6        // dt_rank
#define GG  6        // B * 3 directions
#define NC  200      // scan chunks
#define LC  40       // chunk length
#define ND  38       // dt_rank + 2*d_state

// l -> pos mapping per direction.
__device__ __forceinline__ int pos_from_l(int dir, int l) {
  if (dir == 0) return l;
  int a  = l / 400;
  int r  = l - a * 400;
  int bq = r / 20;
  int cq = r - bq * 20;
  if (dir == 1) return cq * 400 + a * 20 + bq;   // (h=a, w=bq, d=cq)
  return bq * 400 + cq * 20 + a;                 // (w=a, d=bq, h=cq)
}

// ---------------- K0: double LayerNorm over channels (per position) -------
__global__ __launch_bounds__(256) void k_ln2(const float* __restrict__ x,
    const float* __restrict__ lnw, const float* __restrict__ lnb,
    const float* __restrict__ mlnw, const float* __restrict__ mlnb,
    float* __restrict__ xn) {
  int t = blockIdx.x * blockDim.x + threadIdx.x;
  if (t >= BB * S) return;
  int b = t / S, pos = t - b * S;
  const float* xp = x + (size_t)b * CC * S + pos;
  float s1 = 0.f, s2 = 0.f;
  for (int c = 0; c < CC; ++c) { float v = xp[(size_t)c * S]; s1 += v; s2 += v * v; }
  float u = s1 * (1.f / CC);
  float var = s2 * (1.f / CC) - u * u;
  float rstd = rsqrtf(var + 1e-6f);
  float t1 = 0.f, t2 = 0.f;
  for (int c = 0; c < CC; ++c) {
    float y1 = fmaf(lnw[c], (xp[(size_t)c * S] - u) * rstd, lnb[c]);
    t1 += y1; t2 += y1 * y1;
  }
  float u2 = t1 * (1.f / CC);
  float var2 = t2 * (1.f / CC) - u2 * u2;
  float rstd2 = rsqrtf(var2 + 1e-5f);
  float* o = xn + (size_t)t * CC;
  for (int c = 0; c < CC; ++c) {
    float y1 = fmaf(lnw[c], (xp[(size_t)c * S] - u) * rstd, lnb[c]);
    o[c] = fmaf(mlnw[c], (y1 - u2) * rstd2, mlnb[c]);
  }
}

// ---------------- single LayerNorm (B,C,S) -> (B*S,C) --------------------
__global__ __launch_bounds__(256) void k_ln1(const float* __restrict__ xi,
    const float* __restrict__ lnw, const float* __restrict__ lnb,
    float* __restrict__ out) {
  int t = blockIdx.x * blockDim.x + threadIdx.x;
  if (t >= BB * S) return;
  int b = t / S, pos = t - b * S;
  const float* xp = xi + (size_t)b * CC * S + pos;
  float s1 = 0.f, s2 = 0.f;
  for (int c = 0; c < CC; ++c) { float v = xp[(size_t)c * S]; s1 += v; s2 += v * v; }
  float u = s1 * (1.f / CC);
  float var = s2 * (1.f / CC) - u * u;
  float rstd = rsqrtf(var + 1e-6f);
  float* o = out + (size_t)t * CC;
  for (int c = 0; c < CC; ++c)
    o[c] = fmaf(lnw[c], (xp[(size_t)c * S] - u) * rstd, lnb[c]);
}

// ---------------- generic fp32 GEMM: C = act(A[M,K] @ Bw[N,K]^T + bias) ---
template <int ACT, bool BIAS, bool RESID, bool OUT_BCS>
__global__ __launch_bounds__(256) void k_gemm(const float* __restrict__ A,
    const float* __restrict__ Bw, const float* __restrict__ bias,
    const float* __restrict__ resid, float* __restrict__ Cmat,
    int M, int N, int K) {
  __shared__ float As[16][68];
  __shared__ float Bs[16][68];
  int tid = threadIdx.x;
  int tx = tid & 15, ty = tid >> 4;
  int m0 = blockIdx.x * 64, n0 = blockIdx.y * 64;
  float acc[4][4] = {};
  for (int kk = 0; kk < K; kk += 16) {
#pragma unroll
    for (int i = 0; i < 4; ++i) {
      int idx = tid + i * 256;
      int am = idx >> 4, ak = idx & 15;
      As[ak][am] = A[(size_t)(m0 + am) * K + kk + ak];
    }
#pragma unroll
    for (int i = 0; i < 4; ++i) {
      int idx = tid + i * 256;
      int bn = idx >> 4, bk = idx & 15;
      Bs[bk][bn] = (n0 + bn < N) ? Bw[(size_t)(n0 + bn) * K + kk + bk] : 0.f;
    }
    __syncthreads();
#pragma unroll
    for (int k = 0; k < 16; ++k) {
      float4 av = *(const float4*)&As[k][ty * 4];
      float4 bv = *(const float4*)&Bs[k][tx * 4];
      acc[0][0] = fmaf(av.x, bv.x, acc[0][0]);
      acc[0][1] = fmaf(av.x, bv.y, acc[0][1]);
      acc[0][2] = fmaf(av.x, bv.z, acc[0][2]);
      acc[0][3] = fmaf(av.x, bv.w, acc[0][3]);
      acc[1][0] = fmaf(av.y, bv.x, acc[1][0]);
      acc[1][1] = fmaf(av.y, bv.y, acc[1][1]);
      acc[1][2] = fmaf(av.y, bv.z, acc[1][2]);
      acc[1][3] = fmaf(av.y, bv.w, acc[1][3]);
      acc[2][0] = fmaf(av.z, bv.x, acc[2][0]);
      acc[2][1] = fmaf(av.z, bv.y, acc[2][1]);
      acc[2][2] = fmaf(av.z, bv.z, acc[2][2]);
      acc[2][3] = fmaf(av.z, bv.w, acc[2][3]);
      acc[3][0] = fmaf(av.w, bv.x, acc[3][0]);
      acc[3][1] = fmaf(av.w, bv.y, acc[3][1]);
      acc[3][2] = fmaf(av.w, bv.z, acc[3][2]);
      acc[3][3] = fmaf(av.w, bv.w, acc[3][3]);
    }
    __syncthreads();
  }
#pragma unroll
  for (int i = 0; i < 4; ++i) {
    int m = m0 + ty * 4 + i;
#pragma unroll
    for (int j = 0; j < 4; ++j) {
      int n = n0 + tx * 4 + j;
      if (n < N) {
        float v = acc[i][j];
        if (BIAS) v += bias[n];
        if (ACT == 1) v = 0.5f * v * (1.f + erff(v * 0.70710678118654752f));
        if (RESID || OUT_BCS) {
          int bb = m / S, pp = m - bb * S;
          size_t oidx = ((size_t)bb * CC + n) * S + pp;
          if (RESID) v += resid[oidx];
          if (OUT_BCS) { Cmat[oidx] = v; continue; }
        }
        Cmat[(size_t)m * N + n] = v;
      }
    }
  }
}

// ---------------- causal depthwise conv(4) + SiLU, gathered input --------
__global__ __launch_bounds__(256) void k_conv(const float* __restrict__ XZ,
    const float* __restrict__ cw, const float* __restrict__ cb,
    float* __restrict__ xc) {
  int t = blockIdx.x * blockDim.x + threadIdx.x;
  if (t >= GG * S * DI) return;
  int e = t % DI; int gl = t / DI; int l = gl % S; int g = gl / S;
  int b = g / 3, dir = g - (g / 3) * 3;
  float acc = cb[e];
#pragma unroll
  for (int k = 0; k < 4; ++k) {
    int ls = l + k - 3;
    if (ls >= 0) {
      int p = pos_from_l(dir, ls);
      acc = fmaf(cw[e * 4 + k], XZ[((size_t)b * S + p) * 384 + e], acc);
    }
  }
  float sg = 1.f / (1.f + __expf(-acc));
  xc[(size_t)gl * DI + e] = acc * sg;
}

// ======== scan kernels: 1 thread = (g, e, chunk), 16 states in regs ======
// LDS tile: sBC[l][j]: j 0..5 = dt_r, j 8..23 = B, j 24..39 = C (b128-aligned)
__device__ __forceinline__ void stage_bc(float (*sBC)[40],
    const float* __restrict__ xdbl, int g, int c, int tid) {
  const float* src = xdbl + ((size_t)g * S + c * LC) * ND;
  for (int i = tid; i < LC * ND; i += 192) {
    int row = i / ND, col = i - row * ND;
    int dst = (col < RK) ? col : col + 2;
    sBC[row][dst] = src[(size_t)row * ND + col];
  }
}

// common per-step prologue: dt via fast softplus
#define DT_COMMON(l)                                                     \
  float a = bde;                                                         \
  {                                                                      \
    float4 r0 = *(const float4*)&sBC[l][0];                              \
    float2 r1 = *(const float2*)&sBC[l][4];                              \
    a = fmaf(wdt[0], r0.x, a); a = fmaf(wdt[1], r0.y, a);                \
    a = fmaf(wdt[2], r0.z, a); a = fmaf(wdt[3], r0.w, a);                \
    a = fmaf(wdt[4], r1.x, a); a = fmaf(wdt[5], r1.y, a);                \
  }                                                                      \
  float d = fmaxf(a, 0.f) + __logf(1.f + __expf(-fabsf(a)));

__global__ __launch_bounds__(192) void k_scanA(const float* __restrict__ xc,
    const float* __restrict__ xdbl, const float* __restrict__ Wdt,
    const float* __restrict__ bdt, const float* __restrict__ A_log,
    float* __restrict__ PA, float* __restrict__ EA) {
  __shared__ float sBC[LC][40];
  int c = blockIdx.x, g = blockIdx.y;
  int e = threadIdx.x;
  stage_bc(sBC, xdbl, g, c, e);
  float wdt[RK];
#pragma unroll
  for (int r = 0; r < RK; ++r) wdt[r] = Wdt[e * RK + r];
  float bde = bdt[e];
  float Aes[NS];
#pragma unroll
  for (int s = 0; s < NS; ++s) Aes[s] = -__expf(A_log[e * NS + s]);
  float base = Aes[0];
  bool fast = true;
#pragma unroll
  for (int s = 0; s < NS; ++s)
    fast = fast && (fabsf(Aes[s] / base - (float)(s + 1)) < 1e-3f);
  float h[NS];
#pragma unroll
  for (int s = 0; s < NS; ++s) h[s] = 0.f;
  float T = 0.f;
  const float* xptr = xc + ((size_t)g * S + c * LC) * DI + e;
  __syncthreads();
  if (fast) {
    for (int l0 = 0; l0 < LC; l0 += 8) {
      float xb[8];
#pragma unroll
      for (int j = 0; j < 8; ++j) xb[j] = xptr[(size_t)(l0 + j) * DI];
#pragma unroll
      for (int j = 0; j < 8; ++j) {
        int l = l0 + j;
        DT_COMMON(l)
        T += d;
        float w = d * xb[j];
        float4 B0 = *(const float4*)&sBC[l][8];
        float4 B1 = *(const float4*)&sBC[l][12];
        float4 B2 = *(const float4*)&sBC[l][16];
        float4 B3 = *(const float4*)&sBC[l][20];
        float r = __expf(d * base);
        float q = r;
        h[0]=fmaf(q,h[0],w*B0.x); q*=r; h[1]=fmaf(q,h[1],w*B0.y); q*=r;
        h[2]=fmaf(q,h[2],w*B0.z); q*=r; h[3]=fmaf(q,h[3],w*B0.w); q*=r;
        h[4]=fmaf(q,h[4],w*B1.x); q*=r; h[5]=fmaf(q,h[5],w*B1.y); q*=r;
        h[6]=fmaf(q,h[6],w*B1.z); q*=r; h[7]=fmaf(q,h[7],w*B1.w); q*=r;
        h[8]=fmaf(q,h[8],w*B2.x); q*=r; h[9]=fmaf(q,h[9],w*B2.y); q*=r;
        h[10]=fmaf(q,h[10],w*B2.z); q*=r; h[11]=fmaf(q,h[11],w*B2.w); q*=r;
        h[12]=fmaf(q,h[12],w*B3.x); q*=r; h[13]=fmaf(q,h[13],w*B3.y); q*=r;
        h[14]=fmaf(q,h[14],w*B3.z); q*=r; h[15]=fmaf(q,h[15],w*B3.w);
      }
    }
  } else {
    for (int l0 = 0; l0 < LC; l0 += 8) {
      float xb[8];
#pragma unroll
      for (int j = 0; j < 8; ++j) xb[j] = xptr[(size_t)(l0 + j) * DI];
#pragma unroll
      for (int j = 0; j < 8; ++j) {
        int l = l0 + j;
        DT_COMMON(l)
        T += d;
        float w = d * xb[j];
        float4 B0 = *(const float4*)&sBC[l][8];
        float4 B1 = *(const float4*)&sBC[l][12];
        float4 B2 = *(const float4*)&sBC[l][16];
        float4 B3 = *(const float4*)&sBC[l][20];
        float bs[16] = {B0.x, B0.y, B0.z, B0.w, B1.x, B1.y, B1.z, B1.w,
                        B2.x, B2.y, B2.z, B2.w, B3.x, B3.y, B3.z, B3.w};
#pragma unroll
        for (int s = 0; s < NS; ++s) {
          float q = __expf(d * Aes[s]);
          h[s] = fmaf(q, h[s], w * bs[s]);
        }
      }
    }
  }
  float* pp = PA + (((size_t)g * NC + c) * DI + e) * NS;
  float* ep = EA + (((size_t)g * NC + c) * DI + e) * NS;
  float po[NS];
  if (fast) {
    float rT = __expf(base * T);
    float qT = rT;
#pragma unroll
    for (int s = 0; s < NS; ++s) { po[s] = qT; qT *= rT; }
  } else {
#pragma unroll
    for (int s = 0; s < NS; ++s) po[s] = __expf(Aes[s] * T);
  }
#pragma unroll
  for (int s = 0; s < NS; s += 4) {
    *(float4*)&pp[s] = make_float4(po[s], po[s+1], po[s+2], po[s+3]);
    *(float4*)&ep[s] = make_float4(h[s], h[s+1], h[s+2], h[s+3]);
  }
}

// inter-chunk sequential combine (Hin may alias PA: group loads precede stores)
__global__ __launch_bounds__(256) void k_scanB(const float* __restrict__ PA,
    const float* __restrict__ EA, float* __restrict__ Hin) {
  int idx = blockIdx.x * blockDim.x + threadIdx.x;
  if (idx >= GG * DI * NS) return;
  int g = idx / (DI * NS); int es = idx - g * (DI * NS);
  size_t stride = (size_t)DI * NS;
  size_t b0 = (size_t)g * NC * stride + es;
  float h = 0.f;
  for (int c0 = 0; c0 < NC; c0 += 8) {
    float p8[8], e8[8];
#pragma unroll
    for (int j = 0; j < 8; ++j) {
      size_t ix = b0 + (size_t)(c0 + j) * stride;
      p8[j] = PA[ix]; e8[j] = EA[ix];
    }
#pragma unroll
    for (int j = 0; j < 8; ++j) {
      size_t ix = b0 + (size_t)(c0 + j) * stride;
      Hin[ix] = h;
      h = fmaf(p8[j], h, e8[j]);
    }
  }
}

__global__ __launch_bounds__(192) void k_scanC(const float* __restrict__ xc,
    const float* __restrict__ xdbl, const float* __restrict__ Wdt,
    const float* __restrict__ bdt, const float* __restrict__ A_log,
    const float* __restrict__ Hin, const float* __restrict__ Dp,
    float* __restrict__ yg) {
  __shared__ float sBC[LC][40];
  int c = blockIdx.x, g = blockIdx.y;
  int e = threadIdx.x;
  const float* hp = Hin + (((size_t)g * NC + c) * DI + e) * NS;
  float4 h0 = *(const float4*)(hp + 0);
  float4 h1v = *(const float4*)(hp + 4);
  float4 h2v = *(const float4*)(hp + 8);
  float4 h3v = *(const float4*)(hp + 12);
  stage_bc(sBC, xdbl, g, c, e);
  float wdt[RK];
#pragma unroll
  for (int r = 0; r < RK; ++r) wdt[r] = Wdt[e * RK + r];
  float bde = bdt[e];
  float dpe = Dp[e];
  float Aes[NS];
#pragma unroll
  for (int s = 0; s < NS; ++s) Aes[s] = -__expf(A_log[e * NS + s]);
  float base = Aes[0];
  bool fast = true;
#pragma unroll
  for (int s = 0; s < NS; ++s)
    fast = fast && (fabsf(Aes[s] / base - (float)(s + 1)) < 1e-3f);
  float h[NS] = {h0.x, h0.y, h0.z, h0.w, h1v.x, h1v.y, h1v.z, h1v.w,
                 h2v.x, h2v.y, h2v.z, h2v.w, h3v.x, h3v.y, h3v.z, h3v.w};
  const float* xptr = xc + ((size_t)g * S + c * LC) * DI + e;
  int b = g / 3, dir = g - (g / 3) * 3;
  float* yo = yg + ((size_t)b * S + c * LC) * 576 + dir * DI + e;
  __syncthreads();
  if (fast) {
    for (int l0 = 0; l0 < LC; l0 += 8) {
      float xb[8];
#pragma unroll
      for (int j = 0; j < 8; ++j) xb[j] = xptr[(size_t)(l0 + j) * DI];
#pragma unroll
      for (int j = 0; j < 8; ++j) {
        int l = l0 + j;
        DT_COMMON(l)
        float xv = xb[j];
        float w = d * xv;
        float4 B0 = *(const float4*)&sBC[l][8];
        float4 B1 = *(const float4*)&sBC[l][12];
        float4 B2 = *(const float4*)&sBC[l][16];
        float4 B3 = *(const float4*)&sBC[l][20];
        float4 C0 = *(const float4*)&sBC[l][24];
        float4 C1 = *(const float4*)&sBC[l][28];
        float4 C2 = *(const float4*)&sBC[l][32];
        float4 C3 = *(const float4*)&sBC[l][36];
        float r = __expf(d * base);
        float q = r;
        float y0 = xv * dpe, y1 = 0.f, y2 = 0.f, y3 = 0.f;
        h[0]=fmaf(q,h[0],w*B0.x); y0=fmaf(h[0],C0.x,y0); q*=r;
        h[1]=fmaf(q,h[1],w*B0.y); y1=fmaf(h[1],C0.y,y1); q*=r;
        h[2]=fmaf(q,h[2],w*B0.z); y2=fmaf(h[2],C0.z,y2); q*=r;
        h[3]=fmaf(q,h[3],w*B0.w); y3=fmaf(h[3],C0.w,y3); q*=r;
        h[4]=fmaf(q,h[4],w*B1.x); y0=fmaf(h[4],C1.x,y0); q*=r;
        h[5]=fmaf(q,h[5],w*B1.y); y1=fmaf(h[5],C1.y,y1); q*=r;
        h[6]=fmaf(q,h[6],w*B1.z); y2=fmaf(h[6],C1.z,y2); q*=r;
        h[7]=fmaf(q,h[7],w*B1.w); y3=fmaf(h[7],C1.w,y3); q*=r;
        h[8]=fmaf(q,h[8],w*B2.x); y0=fmaf(h[8],C2.x,y0); q*=r;
        h[9]=fmaf(q,h[9],w*B2.y); y1=fmaf(h[9],C2.y,y1); q*=r;
        h[10]=fmaf(q,h[10],w*B2.z); y2=fmaf(h[10],C2.z,y2); q*=r;
        h[11]=fmaf(q,h[11],w*B2.w); y3=fmaf(h[11],C2.w,y3); q*=r;
        h[12]=fmaf(q,h[12],w*B3.x); y0=fmaf(h[12],C3.x,y0); q*=r;
        h[13]=fmaf(q,h[13],w*B3.y); y1=fmaf(h[13],C3.y,y1); q*=r;
        h[14]=fmaf(q,h[14],w*B3.z); y2=fmaf(h[14],C3.z,y2); q*=r;
        h[15]=fmaf(q,h[15],w*B3.w); y3=fmaf(h[15],C3.w,y3);
        yo[(size_t)l * 576] = (y0 + y1) + (y2 + y3);
      }
    }
  } else {
    for (int l0 = 0; l0 < LC; l0 += 8) {
      float xb[8];
#pragma unroll
      for (int j = 0; j < 8; ++j) xb[j] = xptr[(size_t)(l0 + j) * DI];
#pragma unroll
      for (int j = 0; j < 8; ++j) {
        int l = l0 + j;
        DT_COMMON(l)
        float xv = xb[j];
        float w = d * xv;
        float4 B0 = *(const float4*)&sBC[l][8];
        float4 B1 = *(const float4*)&sBC[l][12];
        float4 B2 = *(const float4*)&sBC[l][16];
        float4 B3 = *(const float4*)&sBC[l][20];
        float4 C0 = *(const float4*)&sBC[l][24];
        float4 C1 = *(const float4*)&sBC[l][28];
        float4 C2 = *(const float4*)&sBC[l][32];
        float4 C3 = *(const float4*)&sBC[l][36];
        float bs[16] = {B0.x, B0.y, B0.z, B0.w, B1.x, B1.y, B1.z, B1.w,
                        B2.x, B2.y, B2.z, B2.w, B3.x, B3.y, B3.z, B3.w};
        float cs[16] = {C0.x, C0.y, C0.z, C0.w, C1.x, C1.y, C1.z, C1.w,
                        C2.x, C2.y, C2.z, C2.w, C3.x, C3.y, C3.z, C3.w};
        float y0 = xv * dpe, y1 = 0.f, y2 = 0.f, y3 = 0.f;
#pragma unroll
        for (int s = 0; s < NS; s += 4) {
          float q0 = __expf(d * Aes[s + 0]);
          float q1 = __expf(d * Aes[s + 1]);
          float q2 = __expf(d * Aes[s + 2]);
          float q3 = __expf(d * Aes[s + 3]);
          h[s + 0] = fmaf(q0, h[s + 0], w * bs[s + 0]);
          h[s + 1] = fmaf(q1, h[s + 1], w * bs[s + 1]);
          h[s + 2] = fmaf(q2, h[s + 2], w * bs[s + 2]);
          h[s + 3] = fmaf(q3, h[s + 3], w * bs[s + 3]);
          y0 = fmaf(h[s + 0], cs[s + 0], y0);
          y1 = fmaf(h[s + 1], cs[s + 1], y1);
          y2 = fmaf(h[s + 2], cs[s + 2], y2);
          y3 = fmaf(h[s + 3], cs[s + 3], y3);
        }
        yo[(size_t)l * 576] = (y0 + y1) + (y2 + y3);
      }
    }
  }
}

// ---------------- gate pass: yg *= silu(z gathered) ----------------------
__global__ __launch_bounds__(256) void k_gate(float* __restrict__ yg,
    const float* __restrict__ XZ) {
  int t = blockIdx.x * blockDim.x + threadIdx.x;
  if (t >= BB * S * 144) return;
  int row = t / 144;
  int j4 = t - row * 144;
  int j0 = j4 * 4;
  int dir = j0 / 192; int e0 = j0 - dir * 192;
  int b = row / S; int l = row - b * S;
  int p = pos_from_l(dir, l);
  const float4 z4 = *(const float4*)&XZ[((size_t)b * S + p) * 384 + DI + e0];
  float4* yp = (float4*)(yg + (size_t)row * 576 + j0);
  float4 y4 = *yp;
  y4.x *= z4.x / (1.f + __expf(-z4.x));
  y4.y *= z4.y / (1.f + __expf(-z4.y));
  y4.z *= z4.z / (1.f + __expf(-z4.z));
  y4.w *= z4.w / (1.f + __expf(-z4.w));
  *yp = y4;
}

// ---------------- fold Wout into proj_w: Mcat[o, dir*192+e] --------------
__global__ __launch_bounds__(256) void k_foldW(const float* __restrict__ proj_w,
    const float* __restrict__ Wout, float* __restrict__ Mcat) {
  int t = blockIdx.x * blockDim.x + threadIdx.x;
  if (t >= CC * 576) return;
  int o = t / 576; int j = t - o * 576; int dir = j / DI; int e = j - dir * DI;
  float a = 0.f;
  for (int c2 = 0; c2 < CC; ++c2)
    a = fmaf(proj_w[o * 288 + dir * CC + c2], Wout[c2 * DI + e], a);
  Mcat[t] = a;
}

extern "C" void kernel_launch(void* const* d_in, const int* in_sizes, int n_in,
                              void* d_out, int out_size, void* d_ws, size_t ws_size,
                              hipStream_t stream) {
  const float* x      = (const float*)d_in[0];
  const float* ln_w   = (const float*)d_in[1];
  const float* ln_b   = (const float*)d_in[2];
  const float* mln_w  = (const float*)d_in[3];
  const float* mln_b  = (const float*)d_in[4];
  const float* Win    = (const float*)d_in[5];
  const float* conv_w = (const float*)d_in[6];
  const float* conv_b = (const float*)d_in[7];
  const float* Wx     = (const float*)d_in[8];
  const float* Wdt    = (const float*)d_in[9];
  const float* bdt    = (const float*)d_in[10];
  const float* A_log  = (const float*)d_in[11];
  const float* Dp     = (const float*)d_in[12];
  const float* Wout   = (const float*)d_in[13];
  const float* proj_w = (const float*)d_in[14];
  const float* proj_b = (const float*)d_in[15];
  const float* fc1_w  = (const float*)d_in[16];
  const float* fc1_b  = (const float*)d_in[17];
  const float* fc2_w  = (const float*)d_in[18];
  const float* fc2_b  = (const float*)d_in[19];

  float* ws = (float*)d_ws;
  size_t off = 0;
  float* xn   = ws + off; off += (size_t)BB * S * CC;       // 1.536M
  float* XZ   = ws + off; off += (size_t)BB * S * 384;      // 6.144M
  float* xc   = ws + off; off += (size_t)GG * S * DI;       // 9.216M
  float* xdbl = ws + off; off += (size_t)GG * S * ND;       // 1.824M
  float* PA   = ws + off; off += (size_t)GG * NC * DI * NS; // 3.6864M
  float* EA   = ws + off; off += (size_t)GG * NC * DI * NS; // 3.6864M
  float* yg   = ws + off; off += (size_t)BB * S * 576;      // 9.216M
  float* Mcat = ws + off; off += (size_t)CC * 576;
  if (ws_size < off * sizeof(float)) return;                // ~142 MB; guard
  float* Hin  = PA;     // in-place in scanB (group loads precede stores)
  float* ores = xn;     // xn dead after Win GEMM
  float* xln2 = xc;     // xc dead after scanC
  float* h1   = XZ;     // XZ dead after gate

  k_ln2<<<(BB * S + 255) / 256, 256, 0, stream>>>(x, ln_w, ln_b, mln_w, mln_b, xn);
  k_gemm<0, false, false, false><<<dim3(BB * S / 64, 384 / 64), 256, 0, stream>>>(
      xn, Win, nullptr, nullptr, XZ, BB * S, 384, CC);
  k_conv<<<(GG * S * DI + 255) / 256, 256, 0, stream>>>(XZ, conv_w, conv_b, xc);
  k_gemm<0, false, false, false><<<dim3(GG * S / 64, 1), 256, 0, stream>>>(
      xc, Wx, nullptr, nullptr, xdbl, GG * S, ND, DI);
  k_scanA<<<dim3(NC, GG), 192, 0, stream>>>(xc, xdbl, Wdt, bdt, A_log, PA, EA);
  k_scanB<<<(GG * DI * NS + 255) / 256, 256, 0, stream>>>(PA, EA, Hin);
  k_scanC<<<dim3(NC, GG), 192, 0, stream>>>(xc, xdbl, Wdt, bdt, A_log, Hin, Dp, yg);
  k_gate<<<(BB * S * 144 + 255) / 256, 256, 0, stream>>>(yg, XZ);
  k_foldW<<<(CC * 576 + 255) / 256, 256, 0, stream>>>(proj_w, Wout, Mcat);
  k_gemm<0, true, true, true><<<dim3(BB * S / 64, 2), 256, 0, stream>>>(
      yg, Mcat, proj_b, x, ores, BB * S, CC, 576);
  k_ln1<<<(BB * S + 255) / 256, 256, 0, stream>>>(ores, ln_w, ln_b, xln2);
  k_gemm<1, true, false, false><<<dim3(BB * S / 64, 384 / 64), 256, 0, stream>>>(
      xln2, fc1_w, fc1_b, nullptr, h1, BB * S, 384, CC);
  k_gemm<0, true, true, true><<<dim3(BB * S / 64, 2), 256, 0, stream>>>(
      h1, fc2_w, fc2_b, ores, (float*)d_out, BB * S, CC, 384);
}